// Round 5
// baseline (254.374 us; speedup 1.0000x reference)
//
#include <hip/hip_runtime.h>
#include <hip/hip_bf16.h>
#include <cstdint>
#include <cstddef>

using bf16 = __hip_bfloat16;
typedef __attribute__((ext_vector_type(8))) short short8;
typedef __attribute__((ext_vector_type(4))) float f32x4;
typedef __attribute__((ext_vector_type(16))) float f32x16;

#define T_SEQ 2048
#define NHEAD 16
#define NKV 4
#define HD 128
#define CE 2048

__device__ __forceinline__ void gl_lds16(const void* g, void* l) {
  __builtin_amdgcn_global_load_lds(
      (const __attribute__((address_space(1))) unsigned int*)g,
      (__attribute__((address_space(3))) unsigned int*)l, 16, 0, 0);
}

__device__ __forceinline__ unsigned int cvtpk_bf16(float lo, float hi) {
  unsigned int r;
  asm("v_cvt_pk_bf16_f32 %0, %1, %2" : "=v"(r) : "v"(lo), "v"(hi));
  return r;
}

__device__ __forceinline__ void plswap(unsigned int& x, unsigned int& y, int hi) {
#if __has_builtin(__builtin_amdgcn_permlane32_swap)
  auto r = __builtin_amdgcn_permlane32_swap(x, y, false, false);
  x = r[0];
  y = r[1];
#else
  unsigned int xp = (unsigned int)__shfl_xor((int)x, 32);
  unsigned int yp = (unsigned int)__shfl_xor((int)y, 32);
  unsigned int nx = hi ? yp : x;
  unsigned int ny = hi ? y : xp;
  x = nx;
  y = ny;
#endif
}

// ---------------- elementwise f32 -> bf16 ----------------
__global__ void __launch_bounds__(256) cvt_bf16(const float* __restrict__ in,
                                                bf16* __restrict__ out, int n4) {
  const int i = blockIdx.x * blockDim.x + threadIdx.x;
  if (i >= n4) return;
  const float4 v = ((const float4*)in)[i];
  bf16 b0 = __float2bfloat16(v.x), b1 = __float2bfloat16(v.y),
       b2 = __float2bfloat16(v.z), b3 = __float2bfloat16(v.w);
  ushort4 u;
  u.x = *(const unsigned short*)&b0; u.y = *(const unsigned short*)&b1;
  u.z = *(const unsigned short*)&b2; u.w = *(const unsigned short*)&b3;
  ((ushort4*)out)[i] = u;
}

// ---------------- transpose + convert: Wt[n][k] = W[k][n], K rows = 2048 ----------------
__global__ void __launch_bounds__(256) transpose_cvt(const float* __restrict__ W,
                                                     bf16* __restrict__ Wt, int N) {
  __shared__ float tile[32][33];
  const int tx = threadIdx.x & 31, ty = threadIdx.x >> 5;  // 32 x 8
  const int bx = blockIdx.x, by = blockIdx.y;
#pragma unroll
  for (int i = 0; i < 4; i++) {
    const int r = by * 32 + ty + i * 8;
    tile[ty + i * 8][tx] = W[(size_t)r * N + bx * 32 + tx];
  }
  __syncthreads();
#pragma unroll
  for (int i = 0; i < 4; i++) {
    const int n = bx * 32 + ty + i * 8;
    Wt[(size_t)n * 2048 + by * 32 + tx] = __float2bfloat16(tile[tx][ty + i * 8]);
  }
}

// ---------------- 4-phase (m201-faithful) GEMM: C = A(bf16 MxK) @ Bt(bf16 NxK)^T -------
// 512 thr / 8 waves (WM x WN over quadrant-halves), BK=64, double-buffered LDS.
// Per tile: P1{stage A0'; read a0,b0; MFMA00} P2{stage B0'+A1'; read a1; MFMA10;
// vmcnt(G1N)} P3{stage B1'; read b1; MFMA11} P4{MFMA01 reg-only; vmcnt(G2N)}.
// Gate derivation (per-wave load counts): G1N = loads(P1)+loads(P2) covers the
// B1 half staged at P3(t-1) before P3(t) reads it; G2N = loads(P3) covers
// A0/B0/A1 of t+1 before P1/P2(t+1). No vmcnt(0) in the loop.
template <int BM, int BN, int WM, int WN, bool OBF>
__global__ void __launch_bounds__(512, 2)
gemm4p(const bf16* __restrict__ A, const bf16* __restrict__ Bt,
       void* __restrict__ Cv, int M, int N, int K) {
  constexpr int AWS = BM / 2 / WM;  // wave M-span within a half
  constexpr int BWS = BN / 2 / WN;
  constexpr int MH = AWS / 16;      // A frags per quadrant
  constexpr int NH = BWS / 16;
  constexpr int AL = BM / 64;       // stage loads per thread per tile
  constexpr int BL = BN / 64;
  constexpr int AH = AL / 2;        // per half
  constexpr int BH = BL / 2;
  constexpr int G1N = AH + (BH + AH);  // issued at P1+P2
  constexpr int G2N = BH;              // issued at P3
  __shared__ bf16 smA[2][BM * 64];
  __shared__ bf16 smB[2][BN * 64];

  const int tid = threadIdx.x, lane = tid & 63, wid = tid >> 6;
  const int l15 = lane & 15, l4 = lane >> 4;
  const int wr = wid / WN, wc = wid % WN;

  // bijective XCD-aware block swizzle
  const int nwg = gridDim.x;
  const int q = nwg >> 3, r = nwg & 7;
  const int xcd = blockIdx.x & 7, lin = blockIdx.x >> 3;
  const int wg = (xcd < r ? xcd * (q + 1) : r * (q + 1) + (xcd - r) * q) + lin;
  const int gw = N / BN;
  const int by = wg / gw, bx = wg % gw;
  const int row0 = by * BM, col0 = bx * BN;
  const int NT = K >> 6;

  const bf16* Ag = A + (size_t)row0 * K;
  const bf16* Bg = Bt + (size_t)col0 * K;

  auto stA = [&](int t, int h, int pb) {
    const int k0 = t << 6;
#pragma unroll
    for (int j = 0; j < AH; j++) {
      const int c = (h * AH + j) * 512 + tid;
      const int rowi = c >> 3;
      gl_lds16(Ag + (size_t)rowi * K + k0 + (((c & 7) ^ (rowi & 7)) << 3),
               (void*)(&smA[pb][(size_t)c << 3]));
    }
  };
  auto stB = [&](int t, int h, int pb) {
    const int k0 = t << 6;
#pragma unroll
    for (int j = 0; j < BH; j++) {
      const int c = (h * BH + j) * 512 + tid;
      const int rowi = c >> 3;
      gl_lds16(Bg + (size_t)rowi * K + k0 + (((c & 7) ^ (rowi & 7)) << 3),
               (void*)(&smB[pb][(size_t)c << 3]));
    }
  };
  auto rdA = [&](const bf16* sA, int mh, short8 (&dst)[MH][2]) {
#pragma unroll
    for (int i = 0; i < MH; i++) {
      const int rowl = mh * (BM / 2) + wr * AWS + i * 16 + l15;
#pragma unroll
      for (int kk = 0; kk < 2; kk++)
        dst[i][kk] = *(const short8*)(sA + rowl * 64 +
                                      ((((kk << 2) | l4) ^ (rowl & 7)) << 3));
    }
  };
  auto rdB = [&](const bf16* sB, int nh, short8 (&dst)[NH][2]) {
#pragma unroll
    for (int j = 0; j < NH; j++) {
      const int rowl = nh * (BN / 2) + wc * BWS + j * 16 + l15;
#pragma unroll
      for (int kk = 0; kk < 2; kk++)
        dst[j][kk] = *(const short8*)(sB + rowl * 64 +
                                      ((((kk << 2) | l4) ^ (rowl & 7)) << 3));
    }
  };

  f32x4 acc[2][2][MH][NH];
#pragma unroll
  for (int mh = 0; mh < 2; mh++)
#pragma unroll
    for (int nh = 0; nh < 2; nh++)
#pragma unroll
      for (int i = 0; i < MH; i++)
#pragma unroll
        for (int j = 0; j < NH; j++) acc[mh][nh][i][j] = (f32x4){0.f, 0.f, 0.f, 0.f};

  auto mmq = [&](short8 (&a)[MH][2], short8 (&b)[NH][2], f32x4 (&ac)[MH][NH]) {
    __builtin_amdgcn_s_setprio(1);
#pragma unroll
    for (int i = 0; i < MH; i++)
#pragma unroll
      for (int j = 0; j < NH; j++)
#pragma unroll
        for (int kk = 0; kk < 2; kk++)
          ac[i][j] = __builtin_amdgcn_mfma_f32_16x16x32_bf16(a[i][kk], b[j][kk],
                                                             ac[i][j], 0, 0, 0);
    __builtin_amdgcn_s_setprio(0);
  };

  short8 a0[MH][2], a1[MH][2], b0[NH][2], b1[NH][2];

  // prologue: full tile 0 into buf0
  stA(0, 0, 0); stA(0, 1, 0); stB(0, 0, 0); stB(0, 1, 0);
  asm volatile("s_waitcnt vmcnt(0)" ::: "memory");
  __builtin_amdgcn_s_barrier();

  for (int t = 0; t < NT; ++t) {
    const int buf = t & 1;
    const bf16* sA = smA[buf];
    const bf16* sB = smB[buf];
    const int tn = (t + 1 < NT) ? t + 1 : t;  // clamped tail (writes unread buf)

    // ---- P1 ----
    stA(tn, 0, buf ^ 1);
    rdA(sA, 0, a0);
    rdB(sB, 0, b0);
    __builtin_amdgcn_s_barrier();
    asm volatile("s_waitcnt lgkmcnt(0)" ::: "memory");
    __builtin_amdgcn_sched_barrier(0);
    mmq(a0, b0, acc[0][0]);
    __builtin_amdgcn_s_barrier();
    // ---- P2 ----
    stB(tn, 0, buf ^ 1);
    stA(tn, 1, buf ^ 1);
    rdA(sA, 1, a1);
    __builtin_amdgcn_s_barrier();
    asm volatile("s_waitcnt lgkmcnt(0)" ::: "memory");
    __builtin_amdgcn_sched_barrier(0);
    mmq(a1, b0, acc[1][0]);
    asm volatile("s_waitcnt vmcnt(%0)" ::"i"(G1N) : "memory");
    __builtin_amdgcn_s_barrier();
    // ---- P3 ----
    stB(tn, 1, buf ^ 1);
    rdB(sB, 1, b1);
    __builtin_amdgcn_s_barrier();
    asm volatile("s_waitcnt lgkmcnt(0)" ::: "memory");
    __builtin_amdgcn_sched_barrier(0);
    mmq(a1, b1, acc[1][1]);
    __builtin_amdgcn_s_barrier();
    // ---- P4 (register-only) ----
    mmq(a0, b1, acc[0][1]);
    asm volatile("s_waitcnt vmcnt(%0)" ::"i"(G2N) : "memory");
    __builtin_amdgcn_s_barrier();
  }

#pragma unroll
  for (int mh = 0; mh < 2; mh++)
#pragma unroll
    for (int nh = 0; nh < 2; nh++)
#pragma unroll
      for (int i = 0; i < MH; i++)
#pragma unroll
        for (int j = 0; j < NH; j++)
#pragma unroll
          for (int rr = 0; rr < 4; rr++) {
            const size_t row = row0 + mh * (BM / 2) + wr * AWS + i * 16 + l4 * 4 + rr;
            const size_t col = col0 + nh * (BN / 2) + wc * BWS + j * 16 + l15;
            if constexpr (OBF)
              ((bf16*)Cv)[row * N + col] = __float2bfloat16(acc[mh][nh][i][j][rr]);
            else
              ((float*)Cv)[row * N + col] = acc[mh][nh][i][j][rr];
          }

  asm volatile("s_waitcnt vmcnt(0)" ::: "memory");  // drain LDS-DMA at teardown
}

// ---------------- RMSNorm + RoPE + layout (bf16 input) ----------------
__global__ void __launch_bounds__(256) qkv_post(const bf16* __restrict__ QKV,
                                                const float* __restrict__ qw,
                                                const float* __restrict__ kw,
                                                bf16* __restrict__ Qo,
                                                bf16* __restrict__ Ko,
                                                bf16* __restrict__ Vto) {
  const int g = blockIdx.x * 4 + (threadIdx.x >> 6);
  const int lane = threadIdx.x & 63;
  const int hh = g % 24;
  const int bt = g / 24;
  const int b = bt >> 11, t = bt & (T_SEQ - 1);
  int off;
  if (hh < 16) off = hh * 128;
  else if (hh < 20) off = 2048 + (hh - 16) * 128;
  else off = 2560 + (hh - 20) * 128;
  const ushort2 xr = *(const ushort2*)(QKV + (size_t)bt * 3072 + off + lane * 2);
  const float xx = __bfloat162float(*(const bf16*)&xr.x);
  const float xy = __bfloat162float(*(const bf16*)&xr.y);
  if (hh < 20) {
    float ss = xx * xx + xy * xy;
    ss += __shfl_xor(ss, 1);  ss += __shfl_xor(ss, 2);  ss += __shfl_xor(ss, 4);
    ss += __shfl_xor(ss, 8);  ss += __shfl_xor(ss, 16); ss += __shfl_xor(ss, 32);
    const float rms = rsqrtf(ss * (1.0f / 128.0f) + 1e-5f);
    const float* w = (hh < 16) ? qw : kw;
    const float x0 = xx * rms * w[lane * 2];
    const float x1 = xy * rms * w[lane * 2 + 1];
    const float inv = exp2f((float)lane * (-13.287712379549449f / 64.0f));
    const float th = (float)t * inv;
    const float sn = sinf(th), cs = cosf(th);
    const float y0 = x0 * cs - x1 * sn;
    const float y1 = x0 * sn + x1 * cs;
    const bf16 o0 = __float2bfloat16(y0), o1 = __float2bfloat16(y1);
    if (hh < 16) {
      bf16* d = Qo + ((size_t)(b * NHEAD + hh) * T_SEQ + t) * HD + lane * 2;
      d[0] = o0; d[1] = o1;
    } else {
      bf16* d = Ko + ((size_t)(b * NKV + (hh - 16)) * T_SEQ + t) * HD + lane * 2;
      d[0] = o0; d[1] = o1;
    }
  } else {
    bf16* d = Vto + ((size_t)(b * NKV + (hh - 20)) * HD + lane * 2) * T_SEQ + t;
    d[0] = __float2bfloat16(xx);
    d[T_SEQ] = __float2bfloat16(xy);
  }
}

// ---------------- GQA causal flash attention, swapped-operand 32x32 MFMA ----------------
__global__ void __launch_bounds__(256, 2) attn_fwd(const bf16* __restrict__ Q,
                                                   const bf16* __restrict__ K,
                                                   const bf16* __restrict__ Vt,
                                                   bf16* __restrict__ Y) {
  __shared__ bf16 smK[128 * 128];
  __shared__ bf16 smV[128 * 128];

  const int bid = blockIdx.x;
  const int p = bid & 255, sdx = bid >> 8;
  const int bh = p & 31;
  const int jh = p >> 5;
  const int jq = sdx ? (15 - jh) : jh;
  const int h = bh & (NHEAD - 1), b = bh >> 4;
  const int bkv = b * NKV + (h >> 2);

  const int tid = threadIdx.x, wid = tid >> 6, lane = tid & 63;
  const int l31 = lane & 31, hi = lane >> 5;
  const int q0w = jq * 128 + wid * 32;

  const bf16* Kb = K + (size_t)bkv * T_SEQ * HD;
  const bf16* Vb = Vt + (size_t)bkv * HD * T_SEQ;

  const bf16* Qrow = Q + ((size_t)bh * T_SEQ + q0w + l31) * HD + hi * 8;
  short8 qf[8];
#pragma unroll
  for (int ds = 0; ds < 8; ds++) qf[ds] = *(const short8*)(Qrow + ds * 16);

  f32x16 o[4];
#pragma unroll
  for (int d = 0; d < 4; d++) o[d] = (f32x16)(0.f);
  float mrun = -INFINITY, lrun = 0.f;

  constexpr float CL = 0.08838834764831845f * 1.44269504088896340736f;
  const int trow = tid >> 4, tslot = tid & 15;

  for (int t = 0; t <= jq; t++) {
    const int k0 = t * 128;
    __syncthreads();
#pragma unroll
    for (int i = 0; i < 8; i++) {
      const int row = i * 16 + trow;
      const int ss = (tslot ^ (row & 15)) * 8;
      gl_lds16(Kb + (size_t)(k0 + row) * HD + ss, (void*)((char*)smK + i * 4096 + wid * 1024));
      gl_lds16(Vb + (size_t)row * T_SEQ + k0 + ss, (void*)((char*)smV + i * 4096 + wid * 1024));
    }
    __syncthreads();

    const bool lastt = (t == jq);
    const int glim = lastt ? wid : 3;

    f32x16 sg[4];
#pragma unroll
    for (int g = 0; g < 4; g++) {
      if (g > glim) continue;
      f32x16 acc = (f32x16)(0.f);
#pragma unroll
      for (int ds = 0; ds < 8; ds++) {
        const int row = g * 32 + l31;
        const short8 kf = *(const short8*)(smK + (size_t)row * 128 +
                                           (((ds << 1) | hi) ^ (row & 15)) * 8);
        acc = __builtin_amdgcn_mfma_f32_32x32x16_bf16(kf, qf[ds], acc, 0, 0, 0);
      }
      sg[g] = acc;
    }
    float tmax = -INFINITY;
#pragma unroll
    for (int g = 0; g < 4; g++) {
      if (g > glim) continue;
      if (lastt && g == wid) {
#pragma unroll
        for (int r = 0; r < 16; r++) {
          const int kr = (r & 3) + 8 * (r >> 2) + (hi << 2);
          if (kr > l31) sg[g][r] = -INFINITY;
        }
      }
#pragma unroll
      for (int r = 0; r < 16; r++) tmax = fmaxf(tmax, sg[g][r]);
    }
    tmax = fmaxf(tmax, __shfl_xor(tmax, 32));
    const float mnew = fmaxf(mrun, tmax);
    const float f = exp2f((mrun - mnew) * CL);
    mrun = mnew;
    lrun *= f;
#pragma unroll
    for (int d = 0; d < 4; d++)
#pragma unroll
      for (int r = 0; r < 16; r++) o[d][r] *= f;

    float lsum = 0.f;
#pragma unroll
    for (int g = 0; g < 4; g++) {
      if (g > glim) continue;
      float pp[16];
      float s0 = 0.f, s1 = 0.f;
#pragma unroll
      for (int r = 0; r < 16; r++) pp[r] = exp2f((sg[g][r] - mnew) * CL);
#pragma unroll
      for (int r = 0; r < 8; r++) { s0 += pp[2 * r]; s1 += pp[2 * r + 1]; }
      lsum += s0 + s1;

      unsigned int w0 = cvtpk_bf16(pp[0], pp[1]),  w2 = cvtpk_bf16(pp[4], pp[5]);
      unsigned int w1 = cvtpk_bf16(pp[2], pp[3]),  w3 = cvtpk_bf16(pp[6], pp[7]);
      unsigned int w4 = cvtpk_bf16(pp[8], pp[9]),  w6 = cvtpk_bf16(pp[12], pp[13]);
      unsigned int w5 = cvtpk_bf16(pp[10], pp[11]), w7 = cvtpk_bf16(pp[14], pp[15]);
      plswap(w0, w2, hi); plswap(w1, w3, hi);
      plswap(w4, w6, hi); plswap(w5, w7, hi);
      union { unsigned int u[4]; short8 s8; } pa0, pa1;
      pa0.u[0] = w0; pa0.u[1] = w1; pa0.u[2] = w2; pa0.u[3] = w3;
      pa1.u[0] = w4; pa1.u[1] = w5; pa1.u[2] = w6; pa1.u[3] = w7;

#pragma unroll
      for (int d = 0; d < 4; d++) {
        const int row = d * 32 + l31;
        const int ks0 = g * 2, ks1 = g * 2 + 1;
        const short8 vf0 = *(const short8*)(smV + (size_t)row * 128 +
                                            (((ks0 << 1) | hi) ^ (row & 15)) * 8);
        const short8 vf1 = *(const short8*)(smV + (size_t)row * 128 +
                                            (((ks1 << 1) | hi) ^ (row & 15)) * 8);
        o[d] = __builtin_amdgcn_mfma_f32_32x32x16_bf16(vf0, pa0.s8, o[d], 0, 0, 0);
        o[d] = __builtin_amdgcn_mfma_f32_32x32x16_bf16(vf1, pa1.s8, o[d], 0, 0, 0);
      }
    }
    lrun += lsum + __shfl_xor(lsum, 32);
  }

  const float inv = 1.0f / lrun;
  bf16* yrow = Y + ((size_t)(b * T_SEQ + q0w + l31)) * CE + h * HD;
#pragma unroll
  for (int d = 0; d < 4; d++) {
#pragma unroll
    for (int rg = 0; rg < 4; rg++) {
      ushort4 u;
      bf16 e0 = __float2bfloat16(o[d][rg * 4 + 0] * inv);
      bf16 e1 = __float2bfloat16(o[d][rg * 4 + 1] * inv);
      bf16 e2 = __float2bfloat16(o[d][rg * 4 + 2] * inv);
      bf16 e3 = __float2bfloat16(o[d][rg * 4 + 3] * inv);
      u.x = *(const unsigned short*)&e0; u.y = *(const unsigned short*)&e1;
      u.z = *(const unsigned short*)&e2; u.w = *(const unsigned short*)&e3;
      *(ushort4*)(yrow + d * 32 + rg * 8 + (hi << 2)) = u;
    }
  }
}

// ---------------- launch ----------------
extern "C" void kernel_launch(void* const* d_in, const int* in_sizes, int n_in,
                              void* d_out, int out_size, void* d_ws, size_t ws_size,
                              hipStream_t stream) {
  const float* x   = (const float*)d_in[0];
  const float* wq  = (const float*)d_in[1];
  const float* wk  = (const float*)d_in[2];
  const float* wv  = (const float*)d_in[3];
  const float* wc  = (const float*)d_in[4];
  const float* qnw = (const float*)d_in[5];
  const float* knw = (const float*)d_in[6];
  float* out = (float*)d_out;

  char* ws = (char*)d_ws;
  bf16*  xb    = (bf16*)(ws);                    // 16 MB
  bf16*  wqkvt = (bf16*)(ws + 16777216);         // 12 MB
  bf16*  wct   = (bf16*)(ws + 29360128);         //  8 MB
  bf16*  qkv   = (bf16*)(ws + 37748736);         // 24 MB (bf16 now)
  bf16*  Qb    = (bf16*)(ws + 88080384);         // 16 MB (B,H,T,D)
  bf16*  Kb    = (bf16*)(ws + 104857600);        //  4 MB (B,KVH,T,D)
  bf16*  Vtb   = (bf16*)(ws + 109051904);        //  4 MB (B,KVH,D,T)
  bf16*  yb    = (bf16*)(ws + 113246208);        // 16 MB

  cvt_bf16<<<8192, 256, 0, stream>>>(x, xb, 2097152);
  transpose_cvt<<<dim3(64, 64), 256, 0, stream>>>(wq, wqkvt, 2048);
  transpose_cvt<<<dim3(16, 64), 256, 0, stream>>>(wk, wqkvt + (size_t)2048 * 2048, 512);
  transpose_cvt<<<dim3(16, 64), 256, 0, stream>>>(wv, wqkvt + (size_t)2560 * 2048, 512);
  transpose_cvt<<<dim3(64, 64), 256, 0, stream>>>(wc, wct, 2048);
  gemm4p<256, 256, 2, 4, true><<<192, 512, 0, stream>>>(xb, wqkvt, qkv, 4096, 3072, 2048);
  qkv_post<<<24576, 256, 0, stream>>>(qkv, qnw, knw, Qb, Kb, Vtb);
  attn_fwd<<<512, 256, 0, stream>>>(Qb, Kb, Vtb, yb);
  gemm4p<128, 256, 2, 4, false><<<256, 512, 0, stream>>>(yb, wct, out, 4096, 2048, 2048);
}

// Round 6
// 228.169 us; speedup vs baseline: 1.1149x; 1.1149x over previous
//
#include <hip/hip_runtime.h>
#include <hip/hip_bf16.h>
#include <cstdint>
#include <cstddef>

using bf16 = __hip_bfloat16;
typedef __attribute__((ext_vector_type(8))) short short8;
typedef __attribute__((ext_vector_type(4))) float f32x4;
typedef __attribute__((ext_vector_type(16))) float f32x16;

#define T_SEQ 2048
#define NHEAD 16
#define NKV 4
#define HD 128
#define CE 2048

__device__ __forceinline__ void gl_lds16(const void* g, void* l) {
  __builtin_amdgcn_global_load_lds(
      (const __attribute__((address_space(1))) unsigned int*)g,
      (__attribute__((address_space(3))) unsigned int*)l, 16, 0, 0);
}

__device__ __forceinline__ unsigned int cvtpk_bf16(float lo, float hi) {
  unsigned int r;
  asm("v_cvt_pk_bf16_f32 %0, %1, %2" : "=v"(r) : "v"(lo), "v"(hi));
  return r;
}

__device__ __forceinline__ void plswap(unsigned int& x, unsigned int& y, int hi) {
#if __has_builtin(__builtin_amdgcn_permlane32_swap)
  auto r = __builtin_amdgcn_permlane32_swap(x, y, false, false);
  x = r[0];
  y = r[1];
#else
  unsigned int xp = (unsigned int)__shfl_xor((int)x, 32);
  unsigned int yp = (unsigned int)__shfl_xor((int)y, 32);
  unsigned int nx = hi ? yp : x;
  unsigned int ny = hi ? y : xp;
  x = nx;
  y = ny;
#endif
}

// ---------------- elementwise f32 -> bf16 ----------------
__global__ void __launch_bounds__(256) cvt_bf16(const float* __restrict__ in,
                                                bf16* __restrict__ out, int n4) {
  const int i = blockIdx.x * blockDim.x + threadIdx.x;
  if (i >= n4) return;
  const float4 v = ((const float4*)in)[i];
  bf16 b0 = __float2bfloat16(v.x), b1 = __float2bfloat16(v.y),
       b2 = __float2bfloat16(v.z), b3 = __float2bfloat16(v.w);
  ushort4 u;
  u.x = *(const unsigned short*)&b0; u.y = *(const unsigned short*)&b1;
  u.z = *(const unsigned short*)&b2; u.w = *(const unsigned short*)&b3;
  ((ushort4*)out)[i] = u;
}

// ---------------- transpose + convert: Wt[n][k] = W[k][n], K rows = 2048 ----------------
__global__ void __launch_bounds__(256) transpose_cvt(const float* __restrict__ W,
                                                     bf16* __restrict__ Wt, int N) {
  __shared__ float tile[32][33];
  const int tx = threadIdx.x & 31, ty = threadIdx.x >> 5;  // 32 x 8
  const int bx = blockIdx.x, by = blockIdx.y;
#pragma unroll
  for (int i = 0; i < 4; i++) {
    const int r = by * 32 + ty + i * 8;
    tile[ty + i * 8][tx] = W[(size_t)r * N + bx * 32 + tx];
  }
  __syncthreads();
#pragma unroll
  for (int i = 0; i < 4; i++) {
    const int n = bx * 32 + ty + i * 8;
    Wt[(size_t)n * 2048 + by * 32 + tx] = __float2bfloat16(tile[tx][ty + i * 8]);
  }
}

// ---------------- m201-derived 8-phase/2-K-tile GEMM ----------------
// 512 thr / 8 waves (WM x WN), BK=64, 2 static buffers (no dynamic buf index).
// Per iter (tiles u=2i in buf0, v=2i+1 in buf1), per phase: {stage ONE half-tile;
// ds_read this quadrant's frags; barrier; lgkmcnt(0); setprio+MFMA; barrier}.
// Stage stream: P1 B1(v)->buf1 | P2 A0(u+2)->buf0 | P3 B0(u+2) | P4 A1(u+2), gate |
//               P5 B1(u+2)    | P6 A0(v+2)->buf1 | P7 B0(v+2) | P8 A1(v+2), gate.
// Each slot is overwritten exactly 1 phase after its read; gate N = 2AH+BH loads
// (3 half-tiles in flight, never drained to 0). Last iter peeled (no stages).
template <int BM, int BN, int WM, int WN, bool OBF>
__global__ void __launch_bounds__(512, 2)
gemm8i(const bf16* __restrict__ A, const bf16* __restrict__ Bt,
       void* __restrict__ Cv, int M, int N, int K) {
  constexpr int AWS = BM / 2 / WM;  // wave M-span within a half
  constexpr int BWS = BN / 2 / WN;
  constexpr int MH = AWS / 16;
  constexpr int NH = BWS / 16;
  constexpr int AH = BM / 128;      // loads/thread per A half-tile
  constexpr int BH = BN / 128;
  constexpr int G = 2 * AH + BH;    // gate: 3 half-tiles in flight
  __shared__ bf16 smA[2][BM * 64];
  __shared__ bf16 smB[2][BN * 64];

  const int tid = threadIdx.x, lane = tid & 63, wid = tid >> 6;
  const int l15 = lane & 15, l4 = lane >> 4;
  const int wr = wid / WN, wc = wid % WN;

  // bijective XCD-aware block swizzle
  const int nwg = gridDim.x;
  const int q = nwg >> 3, r = nwg & 7;
  const int xcd = blockIdx.x & 7, lin = blockIdx.x >> 3;
  const int wg = (xcd < r ? xcd * (q + 1) : r * (q + 1) + (xcd - r) * q) + lin;
  const int gw = N / BN;
  const int by = wg / gw, bx = wg % gw;
  const int row0 = by * BM, col0 = bx * BN;
  const int NT = K >> 6;   // assumed even
  const int NI = NT >> 1;

  const bf16* Ag = A + (size_t)row0 * K;
  const bf16* Bg = Bt + (size_t)col0 * K;

  auto stA = [&](int t, int h, int pb) {
    const int k0 = t << 6;
#pragma unroll
    for (int j = 0; j < AH; j++) {
      const int c = (h * AH + j) * 512 + tid;
      const int rowi = c >> 3;
      gl_lds16(Ag + (size_t)rowi * K + k0 + (((c & 7) ^ (rowi & 7)) << 3),
               (void*)(&smA[pb][(size_t)c << 3]));
    }
  };
  auto stB = [&](int t, int h, int pb) {
    const int k0 = t << 6;
#pragma unroll
    for (int j = 0; j < BH; j++) {
      const int c = (h * BH + j) * 512 + tid;
      const int rowi = c >> 3;
      gl_lds16(Bg + (size_t)rowi * K + k0 + (((c & 7) ^ (rowi & 7)) << 3),
               (void*)(&smB[pb][(size_t)c << 3]));
    }
  };
  auto rdA = [&](const bf16* sA, int mh, short8 (&dst)[MH][2]) {
#pragma unroll
    for (int i = 0; i < MH; i++) {
      const int rowl = mh * (BM / 2) + wr * AWS + i * 16 + l15;
#pragma unroll
      for (int kk = 0; kk < 2; kk++)
        dst[i][kk] = *(const short8*)(sA + rowl * 64 +
                                      ((((kk << 2) | l4) ^ (rowl & 7)) << 3));
    }
  };
  auto rdB = [&](const bf16* sB, int nh, short8 (&dst)[NH][2]) {
#pragma unroll
    for (int j = 0; j < NH; j++) {
      const int rowl = nh * (BN / 2) + wc * BWS + j * 16 + l15;
#pragma unroll
      for (int kk = 0; kk < 2; kk++)
        dst[j][kk] = *(const short8*)(sB + rowl * 64 +
                                      ((((kk << 2) | l4) ^ (rowl & 7)) << 3));
    }
  };

  f32x4 acc[2][2][MH][NH];
#pragma unroll
  for (int mh = 0; mh < 2; mh++)
#pragma unroll
    for (int nh = 0; nh < 2; nh++)
#pragma unroll
      for (int i = 0; i < MH; i++)
#pragma unroll
        for (int j = 0; j < NH; j++) acc[mh][nh][i][j] = (f32x4){0.f, 0.f, 0.f, 0.f};

  auto mmq = [&](short8 (&a)[MH][2], short8 (&b)[NH][2], f32x4 (&ac)[MH][NH]) {
    __builtin_amdgcn_s_setprio(1);
#pragma unroll
    for (int i = 0; i < MH; i++)
#pragma unroll
      for (int j = 0; j < NH; j++)
#pragma unroll
        for (int kk = 0; kk < 2; kk++)
          ac[i][j] = __builtin_amdgcn_mfma_f32_16x16x32_bf16(a[i][kk], b[j][kk],
                                                             ac[i][j], 0, 0, 0);
    __builtin_amdgcn_s_setprio(0);
  };

  short8 a0[MH][2], a1[MH][2], b0[NH][2], b1[NH][2];

#define LGKM0_SB                                            \
  asm volatile("s_waitcnt lgkmcnt(0)" ::: "memory");        \
  __builtin_amdgcn_sched_barrier(0);
#define GATE_G                                              \
  asm volatile("s_waitcnt vmcnt(%0)" ::"i"(G) : "memory");

  // prologue: T0 (4 half-tiles) + A0,B0,A1 of T1 -> gate leaves 3 HT in flight
  stA(0, 0, 0); stB(0, 0, 0); stA(0, 1, 0); stB(0, 1, 0);
  stA(1, 0, 1); stB(1, 0, 1); stA(1, 1, 1);
  GATE_G
  __builtin_amdgcn_s_barrier();

  for (int i = 0; i < NI - 1; ++i) {
    const int u = 2 * i, v = u + 1;
    // ---- P1 ----
    stB(v, 1, 1);
    rdA(smA[0], 0, a0); rdB(smB[0], 0, b0);
    __builtin_amdgcn_s_barrier();
    LGKM0_SB
    mmq(a0, b0, acc[0][0]);
    __builtin_amdgcn_s_barrier();
    // ---- P2 ----
    stA(u + 2, 0, 0);
    rdA(smA[0], 1, a1);
    __builtin_amdgcn_s_barrier();
    LGKM0_SB
    mmq(a1, b0, acc[1][0]);
    __builtin_amdgcn_s_barrier();
    // ---- P3 ----
    stB(u + 2, 0, 0);
    rdB(smB[0], 1, b1);
    __builtin_amdgcn_s_barrier();
    LGKM0_SB
    mmq(a1, b1, acc[1][1]);
    __builtin_amdgcn_s_barrier();
    // ---- P4 (reg-only MFMA; gate) ----
    stA(u + 2, 1, 0);
    mmq(a0, b1, acc[0][1]);
    GATE_G
    __builtin_amdgcn_s_barrier();
    // ---- P5 ----
    stB(u + 2, 1, 0);
    rdA(smA[1], 0, a0); rdB(smB[1], 0, b0);
    __builtin_amdgcn_s_barrier();
    LGKM0_SB
    mmq(a0, b0, acc[0][0]);
    __builtin_amdgcn_s_barrier();
    // ---- P6 ----
    stA(v + 2, 0, 1);
    rdA(smA[1], 1, a1);
    __builtin_amdgcn_s_barrier();
    LGKM0_SB
    mmq(a1, b0, acc[1][0]);
    __builtin_amdgcn_s_barrier();
    // ---- P7 ----
    stB(v + 2, 0, 1);
    rdB(smB[1], 1, b1);
    __builtin_amdgcn_s_barrier();
    LGKM0_SB
    mmq(a1, b1, acc[1][1]);
    __builtin_amdgcn_s_barrier();
    // ---- P8 (reg-only MFMA; gate) ----
    stA(v + 2, 1, 1);
    mmq(a0, b1, acc[0][1]);
    GATE_G
    __builtin_amdgcn_s_barrier();
  }

  // ---- peeled last iter (u=NT-2 in buf0, v=NT-1 in buf1); only B1(v) staged ----
  {
    stB(NT - 1, 1, 1);
    rdA(smA[0], 0, a0); rdB(smB[0], 0, b0);
    __builtin_amdgcn_s_barrier();
    LGKM0_SB
    mmq(a0, b0, acc[0][0]);
    __builtin_amdgcn_s_barrier();
    rdA(smA[0], 1, a1);
    __builtin_amdgcn_s_barrier();
    LGKM0_SB
    mmq(a1, b0, acc[1][0]);
    __builtin_amdgcn_s_barrier();
    rdB(smB[0], 1, b1);
    __builtin_amdgcn_s_barrier();
    LGKM0_SB
    mmq(a1, b1, acc[1][1]);
    __builtin_amdgcn_s_barrier();
    mmq(a0, b1, acc[0][1]);
    asm volatile("s_waitcnt vmcnt(0)" ::: "memory");
    __builtin_amdgcn_s_barrier();
    rdA(smA[1], 0, a0); rdB(smB[1], 0, b0);
    __builtin_amdgcn_s_barrier();
    LGKM0_SB
    mmq(a0, b0, acc[0][0]);
    __builtin_amdgcn_s_barrier();
    rdA(smA[1], 1, a1);
    __builtin_amdgcn_s_barrier();
    LGKM0_SB
    mmq(a1, b0, acc[1][0]);
    __builtin_amdgcn_s_barrier();
    rdB(smB[1], 1, b1);
    __builtin_amdgcn_s_barrier();
    LGKM0_SB
    mmq(a1, b1, acc[1][1]);
    mmq(a0, b1, acc[0][1]);
  }

#pragma unroll
  for (int mh = 0; mh < 2; mh++)
#pragma unroll
    for (int nh = 0; nh < 2; nh++)
#pragma unroll
      for (int i = 0; i < MH; i++)
#pragma unroll
        for (int j = 0; j < NH; j++)
#pragma unroll
          for (int rr = 0; rr < 4; rr++) {
            const size_t row = row0 + mh * (BM / 2) + wr * AWS + i * 16 + l4 * 4 + rr;
            const size_t col = col0 + nh * (BN / 2) + wc * BWS + j * 16 + l15;
            if constexpr (OBF)
              ((bf16*)Cv)[row * N + col] = __float2bfloat16(acc[mh][nh][i][j][rr]);
            else
              ((float*)Cv)[row * N + col] = acc[mh][nh][i][j][rr];
          }
#undef LGKM0_SB
#undef GATE_G
}

// ---------------- RMSNorm + RoPE + layout (bf16 input) ----------------
__global__ void __launch_bounds__(256) qkv_post(const bf16* __restrict__ QKV,
                                                const float* __restrict__ qw,
                                                const float* __restrict__ kw,
                                                bf16* __restrict__ Qo,
                                                bf16* __restrict__ Ko,
                                                bf16* __restrict__ Vto) {
  const int g = blockIdx.x * 4 + (threadIdx.x >> 6);
  const int lane = threadIdx.x & 63;
  const int hh = g % 24;
  const int bt = g / 24;
  const int b = bt >> 11, t = bt & (T_SEQ - 1);
  int off;
  if (hh < 16) off = hh * 128;
  else if (hh < 20) off = 2048 + (hh - 16) * 128;
  else off = 2560 + (hh - 20) * 128;
  const ushort2 xr = *(const ushort2*)(QKV + (size_t)bt * 3072 + off + lane * 2);
  const float xx = __bfloat162float(*(const bf16*)&xr.x);
  const float xy = __bfloat162float(*(const bf16*)&xr.y);
  if (hh < 20) {
    float ss = xx * xx + xy * xy;
    ss += __shfl_xor(ss, 1);  ss += __shfl_xor(ss, 2);  ss += __shfl_xor(ss, 4);
    ss += __shfl_xor(ss, 8);  ss += __shfl_xor(ss, 16); ss += __shfl_xor(ss, 32);
    const float rms = rsqrtf(ss * (1.0f / 128.0f) + 1e-5f);
    const float* w = (hh < 16) ? qw : kw;
    const float x0 = xx * rms * w[lane * 2];
    const float x1 = xy * rms * w[lane * 2 + 1];
    const float inv = exp2f((float)lane * (-13.287712379549449f / 64.0f));
    const float th = (float)t * inv;
    const float sn = sinf(th), cs = cosf(th);
    const float y0 = x0 * cs - x1 * sn;
    const float y1 = x0 * sn + x1 * cs;
    const bf16 o0 = __float2bfloat16(y0), o1 = __float2bfloat16(y1);
    if (hh < 16) {
      bf16* d = Qo + ((size_t)(b * NHEAD + hh) * T_SEQ + t) * HD + lane * 2;
      d[0] = o0; d[1] = o1;
    } else {
      bf16* d = Ko + ((size_t)(b * NKV + (hh - 16)) * T_SEQ + t) * HD + lane * 2;
      d[0] = o0; d[1] = o1;
    }
  } else {
    bf16* d = Vto + ((size_t)(b * NKV + (hh - 20)) * HD + lane * 2) * T_SEQ + t;
    d[0] = __float2bfloat16(xx);
    d[T_SEQ] = __float2bfloat16(xy);
  }
}

// ---------------- GQA causal flash attention, swapped-operand 32x32 MFMA ----------------
__global__ void __launch_bounds__(256, 2) attn_fwd(const bf16* __restrict__ Q,
                                                   const bf16* __restrict__ K,
                                                   const bf16* __restrict__ Vt,
                                                   bf16* __restrict__ Y) {
  __shared__ bf16 smK[128 * 128];
  __shared__ bf16 smV[128 * 128];

  const int bid = blockIdx.x;
  const int p = bid & 255, sdx = bid >> 8;
  const int bh = p & 31;
  const int jh = p >> 5;
  const int jq = sdx ? (15 - jh) : jh;
  const int h = bh & (NHEAD - 1), b = bh >> 4;
  const int bkv = b * NKV + (h >> 2);

  const int tid = threadIdx.x, wid = tid >> 6, lane = tid & 63;
  const int l31 = lane & 31, hi = lane >> 5;
  const int q0w = jq * 128 + wid * 32;

  const bf16* Kb = K + (size_t)bkv * T_SEQ * HD;
  const bf16* Vb = Vt + (size_t)bkv * HD * T_SEQ;

  const bf16* Qrow = Q + ((size_t)bh * T_SEQ + q0w + l31) * HD + hi * 8;
  short8 qf[8];
#pragma unroll
  for (int ds = 0; ds < 8; ds++) qf[ds] = *(const short8*)(Qrow + ds * 16);

  f32x16 o[4];
#pragma unroll
  for (int d = 0; d < 4; d++) o[d] = (f32x16)(0.f);
  float mrun = -INFINITY, lrun = 0.f;

  constexpr float CL = 0.08838834764831845f * 1.44269504088896340736f;
  const int trow = tid >> 4, tslot = tid & 15;

  for (int t = 0; t <= jq; t++) {
    const int k0 = t * 128;
    __syncthreads();
#pragma unroll
    for (int i = 0; i < 8; i++) {
      const int row = i * 16 + trow;
      const int ss = (tslot ^ (row & 15)) * 8;
      gl_lds16(Kb + (size_t)(k0 + row) * HD + ss, (void*)((char*)smK + i * 4096 + wid * 1024));
      gl_lds16(Vb + (size_t)row * T_SEQ + k0 + ss, (void*)((char*)smV + i * 4096 + wid * 1024));
    }
    __syncthreads();

    const bool lastt = (t == jq);
    const int glim = lastt ? wid : 3;

    f32x16 sg[4];
#pragma unroll
    for (int g = 0; g < 4; g++) {
      if (g > glim) continue;
      f32x16 acc = (f32x16)(0.f);
#pragma unroll
      for (int ds = 0; ds < 8; ds++) {
        const int row = g * 32 + l31;
        const short8 kf = *(const short8*)(smK + (size_t)row * 128 +
                                           (((ds << 1) | hi) ^ (row & 15)) * 8);
        acc = __builtin_amdgcn_mfma_f32_32x32x16_bf16(kf, qf[ds], acc, 0, 0, 0);
      }
      sg[g] = acc;
    }
    float tmax = -INFINITY;
#pragma unroll
    for (int g = 0; g < 4; g++) {
      if (g > glim) continue;
      if (lastt && g == wid) {
#pragma unroll
        for (int r = 0; r < 16; r++) {
          const int kr = (r & 3) + 8 * (r >> 2) + (hi << 2);
          if (kr > l31) sg[g][r] = -INFINITY;
        }
      }
#pragma unroll
      for (int r = 0; r < 16; r++) tmax = fmaxf(tmax, sg[g][r]);
    }
    tmax = fmaxf(tmax, __shfl_xor(tmax, 32));
    const float mnew = fmaxf(mrun, tmax);
    const float f = exp2f((mrun - mnew) * CL);
    mrun = mnew;
    lrun *= f;
#pragma unroll
    for (int d = 0; d < 4; d++)
#pragma unroll
      for (int r = 0; r < 16; r++) o[d][r] *= f;

    float lsum = 0.f;
#pragma unroll
    for (int g = 0; g < 4; g++) {
      if (g > glim) continue;
      float pp[16];
      float s0 = 0.f, s1 = 0.f;
#pragma unroll
      for (int r = 0; r < 16; r++) pp[r] = exp2f((sg[g][r] - mnew) * CL);
#pragma unroll
      for (int r = 0; r < 8; r++) { s0 += pp[2 * r]; s1 += pp[2 * r + 1]; }
      lsum += s0 + s1;

      unsigned int w0 = cvtpk_bf16(pp[0], pp[1]),  w2 = cvtpk_bf16(pp[4], pp[5]);
      unsigned int w1 = cvtpk_bf16(pp[2], pp[3]),  w3 = cvtpk_bf16(pp[6], pp[7]);
      unsigned int w4 = cvtpk_bf16(pp[8], pp[9]),  w6 = cvtpk_bf16(pp[12], pp[13]);
      unsigned int w5 = cvtpk_bf16(pp[10], pp[11]), w7 = cvtpk_bf16(pp[14], pp[15]);
      plswap(w0, w2, hi); plswap(w1, w3, hi);
      plswap(w4, w6, hi); plswap(w5, w7, hi);
      union { unsigned int u[4]; short8 s8; } pa0, pa1;
      pa0.u[0] = w0; pa0.u[1] = w1; pa0.u[2] = w2; pa0.u[3] = w3;
      pa1.u[0] = w4; pa1.u[1] = w5; pa1.u[2] = w6; pa1.u[3] = w7;

#pragma unroll
      for (int d = 0; d < 4; d++) {
        const int row = d * 32 + l31;
        const int ks0 = g * 2, ks1 = g * 2 + 1;
        const short8 vf0 = *(const short8*)(smV + (size_t)row * 128 +
                                            (((ks0 << 1) | hi) ^ (row & 15)) * 8);
        const short8 vf1 = *(const short8*)(smV + (size_t)row * 128 +
                                            (((ks1 << 1) | hi) ^ (row & 15)) * 8);
        o[d] = __builtin_amdgcn_mfma_f32_32x32x16_bf16(vf0, pa0.s8, o[d], 0, 0, 0);
        o[d] = __builtin_amdgcn_mfma_f32_32x32x16_bf16(vf1, pa1.s8, o[d], 0, 0, 0);
      }
    }
    lrun += lsum + __shfl_xor(lsum, 32);
  }

  const float inv = 1.0f / lrun;
  bf16* yrow = Y + ((size_t)(b * T_SEQ + q0w + l31)) * CE + h * HD;
#pragma unroll
  for (int d = 0; d < 4; d++) {
#pragma unroll
    for (int rg = 0; rg < 4; rg++) {
      ushort4 u;
      bf16 e0 = __float2bfloat16(o[d][rg * 4 + 0] * inv);
      bf16 e1 = __float2bfloat16(o[d][rg * 4 + 1] * inv);
      bf16 e2 = __float2bfloat16(o[d][rg * 4 + 2] * inv);
      bf16 e3 = __float2bfloat16(o[d][rg * 4 + 3] * inv);
      u.x = *(const unsigned short*)&e0; u.y = *(const unsigned short*)&e1;
      u.z = *(const unsigned short*)&e2; u.w = *(const unsigned short*)&e3;
      *(ushort4*)(yrow + d * 32 + rg * 8 + (hi << 2)) = u;
    }
  }
}

// ---------------- launch ----------------
extern "C" void kernel_launch(void* const* d_in, const int* in_sizes, int n_in,
                              void* d_out, int out_size, void* d_ws, size_t ws_size,
                              hipStream_t stream) {
  const float* x   = (const float*)d_in[0];
  const float* wq  = (const float*)d_in[1];
  const float* wk  = (const float*)d_in[2];
  const float* wv  = (const float*)d_in[3];
  const float* wc  = (const float*)d_in[4];
  const float* qnw = (const float*)d_in[5];
  const float* knw = (const float*)d_in[6];
  float* out = (float*)d_out;

  char* ws = (char*)d_ws;
  bf16*  xb    = (bf16*)(ws);                    // 16 MB
  bf16*  wqkvt = (bf16*)(ws + 16777216);         // 12 MB
  bf16*  wct   = (bf16*)(ws + 29360128);         //  8 MB
  bf16*  qkv   = (bf16*)(ws + 37748736);         // 24 MB
  bf16*  Qb    = (bf16*)(ws + 88080384);         // 16 MB (B,H,T,D)
  bf16*  Kb    = (bf16*)(ws + 104857600);        //  4 MB (B,KVH,T,D)
  bf16*  Vtb   = (bf16*)(ws + 109051904);        //  4 MB (B,KVH,D,T)
  bf16*  yb    = (bf16*)(ws + 113246208);        // 16 MB

  cvt_bf16<<<8192, 256, 0, stream>>>(x, xb, 2097152);
  transpose_cvt<<<dim3(64, 64), 256, 0, stream>>>(wq, wqkvt, 2048);
  transpose_cvt<<<dim3(16, 64), 256, 0, stream>>>(wk, wqkvt + (size_t)2048 * 2048, 512);
  transpose_cvt<<<dim3(16, 64), 256, 0, stream>>>(wv, wqkvt + (size_t)2560 * 2048, 512);
  transpose_cvt<<<dim3(64, 64), 256, 0, stream>>>(wc, wct, 2048);
  gemm8i<256, 256, 2, 4, true><<<192, 512, 0, stream>>>(xb, wqkvt, qkv, 4096, 3072, 2048);
  qkv_post<<<24576, 256, 0, stream>>>(qkv, qnw, knw, Qb, Kb, Vtb);
  attn_fwd<<<512, 256, 0, stream>>>(Qb, Kb, Vtb, yb);
  gemm8i<128, 256, 2, 4, false><<<256, 512, 0, stream>>>(yb, wct, out, 4096, 2048, 2048);
}